// Round 1
// baseline (27.408 us; speedup 1.0000x reference)
//
#include <hip/hip_runtime.h>
#include <math.h>

#define N_ELEMS 8192
#define N_PAIRS 4096
#define SCAN_THREADS 1024
#define CHUNK 4   // N_PAIRS / SCAN_THREADS

// Kernel 1: stable rank (descending target, ties by original index) + scatter.
// One wave (64 lanes) per element j. rank[j] = #{k : t_k > t_j || (t_k == t_j && k < j)}
// fsorted[rank[j]] = pred[j]  ==  f = pred[argsort(-target)] (stable).
__global__ void __launch_bounds__(256) rank_scatter_kernel(
    const float* __restrict__ pred,
    const float* __restrict__ target,
    float* __restrict__ fsorted)
{
    const int wid  = (blockIdx.x * blockDim.x + threadIdx.x) >> 6;  // wave id = element j
    const int lane = threadIdx.x & 63;
    if (wid >= N_ELEMS) return;

    const float tj = target[wid];
    int cnt = 0;
    // lanes stride over k: coalesced, target fully L1/L2 resident (32 KB)
    for (int k = lane; k < N_ELEMS; k += 64) {
        const float tk = target[k];
        cnt += ((tk > tj) || (tk == tj && k < wid)) ? 1 : 0;
    }
    // wave-64 shuffle reduction
    #pragma unroll
    for (int off = 32; off > 0; off >>= 1)
        cnt += __shfl_down(cnt, off, 64);

    if (lane == 0) fsorted[cnt] = pred[wid];
}

// Kernel 2: closed-form loss from sorted f.
//   a_i = e^{f_i} + e^{f_{N-1-i}},  b_i = e^{-f_i} + e^{-f_{N-1-i}},  i in [0, N_PAIRS)
//   E_i = sum_{k>=i} a_k,  G_i = sum_{k>=i} b_k   (suffix sums)
//   denom_i = E_i*G_i - (N - 2i);  if denom<=0 -> 1e-8
//   loss = - sum_i [ (f_i - f_{N-1-i}) - log(denom_i) ]
__global__ void __launch_bounds__(SCAN_THREADS) loss_kernel(
    const float* __restrict__ f,
    float* __restrict__ out)
{
    __shared__ double sA[SCAN_THREADS];
    __shared__ double sB[SCAN_THREADS];

    const int t = threadIdx.x;

    float fi[CHUNK], fo[CHUNK];
    double a[CHUNK], b[CHUNK];
    double sa = 0.0, sb = 0.0;

    #pragma unroll
    for (int c = 0; c < CHUNK; ++c) {
        const int i = CHUNK * t + c;
        fi[c] = f[i];
        fo[c] = f[N_ELEMS - 1 - i];
        const float e1 = expf(fi[c]);
        const float e2 = expf(fo[c]);
        const float m1 = expf(-fi[c]);
        const float m2 = expf(-fo[c]);
        a[c] = (double)e1 + (double)e2;
        b[c] = (double)m1 + (double)m2;
        sa += a[c];
        sb += b[c];
    }

    sA[t] = sa;
    sB[t] = sb;
    __syncthreads();

    // Hillis-Steele inclusive prefix scan over per-thread chunk sums (fp64)
    double va = sa, vb = sb;
    for (int off = 1; off < SCAN_THREADS; off <<= 1) {
        const double pa = (t >= off) ? sA[t - off] : 0.0;
        const double pb = (t >= off) ? sB[t - off] : 0.0;
        __syncthreads();
        va += pa;
        vb += pb;
        sA[t] = va;
        sB[t] = vb;
        __syncthreads();
    }

    const double Ta = sA[SCAN_THREADS - 1];   // total sum of a
    const double Tb = sB[SCAN_THREADS - 1];   // total sum of b
    const double prefExclA = va - sa;         // sum over threads < t
    const double prefExclB = vb - sb;

    double runA = 0.0, runB = 0.0;
    double lsum = 0.0;
    #pragma unroll
    for (int c = 0; c < CHUNK; ++c) {
        const int i = CHUNK * t + c;
        const double E = Ta - prefExclA - runA;   // suffix sum starting at i
        const double G = Tb - prefExclB - runB;
        runA += a[c];
        runB += b[c];
        double denom = E * G - (double)(N_ELEMS - 2 * i);
        if (denom <= 0.0) denom = 1e-8;
        lsum += (double)(fi[c] - fo[c]) - log(denom);
    }

    // block reduction of loss terms (reuse sA)
    __syncthreads();
    sA[t] = lsum;
    __syncthreads();
    for (int off = SCAN_THREADS / 2; off > 0; off >>= 1) {
        if (t < off) sA[t] += sA[t + off];
        __syncthreads();
    }

    if (t == 0) out[0] = (float)(-sA[0]);
}

extern "C" void kernel_launch(void* const* d_in, const int* in_sizes, int n_in,
                              void* d_out, int out_size, void* d_ws, size_t ws_size,
                              hipStream_t stream)
{
    const float* pred   = (const float*)d_in[0];
    const float* target = (const float*)d_in[1];
    float* out = (float*)d_out;
    float* fsorted = (float*)d_ws;   // 8192 floats = 32 KB scratch

    // 8192 waves, 4 waves per 256-thread block -> 2048 blocks
    rank_scatter_kernel<<<N_ELEMS / 4, 256, 0, stream>>>(pred, target, fsorted);
    loss_kernel<<<1, SCAN_THREADS, 0, stream>>>(fsorted, out);
}

// Round 2
// 23.046 us; speedup vs baseline: 1.1893x; 1.1893x over previous
//
#include <hip/hip_runtime.h>
#include <math.h>

#define N 8192
#define NP 4096

// Monotone total-order key for floats: s = bits ^ (sign ? 0xFFFFFFFF : 0x80000000).
// Full key K = (s << 13) | (8191 - k): K_k > K_j  <=>  t_k > t_j || (t_k == t_j && k < j),
// which is exactly the stable descending-argsort rank predicate.
__device__ __forceinline__ unsigned int fkey(float x) {
    unsigned int u = __float_as_uint(x);
    unsigned int m = (unsigned int)((int)u >> 31) | 0x80000000u;
    return u ^ m;
}

__device__ __forceinline__ unsigned long long fullkey(float x, int k) {
    return ((unsigned long long)fkey(x) << 13) | (unsigned long long)(N - 1 - k);
}

// Kernel 1: rank via ballot+popcount. 1024 waves, each owns 8 consecutive j's.
// Per iteration a wave covers 256 k's (float4 per lane); one v_cmp_gt_u64 + ballot
// counts 64 (j,k) pairs. Scatter pred[j] -> fsorted[rank_j].
__global__ void __launch_bounds__(256) rank_kernel(
    const float* __restrict__ pred,
    const float* __restrict__ target,
    float* __restrict__ fsorted)
{
    const int wid  = (blockIdx.x * blockDim.x + threadIdx.x) >> 6;  // 0..1023
    const int lane = threadIdx.x & 63;
    const int jbase = wid * 8;

    // wave-uniform keys for the 8 owned j's (scalar loads / SALU)
    unsigned long long Kj[8];
    #pragma unroll
    for (int jj = 0; jj < 8; ++jj)
        Kj[jj] = fullkey(target[jbase + jj], jbase + jj);

    int cnt[8] = {0, 0, 0, 0, 0, 0, 0, 0};

    #pragma unroll 2
    for (int it = 0; it < N / 256; ++it) {
        const int kb = it * 256 + lane * 4;
        const float4 tv = *reinterpret_cast<const float4*>(target + kb);
        unsigned long long Kk[4];
        Kk[0] = fullkey(tv.x, kb + 0);
        Kk[1] = fullkey(tv.y, kb + 1);
        Kk[2] = fullkey(tv.z, kb + 2);
        Kk[3] = fullkey(tv.w, kb + 3);
        #pragma unroll
        for (int jj = 0; jj < 8; ++jj) {
            cnt[jj] += __popcll(__ballot(Kk[0] > Kj[jj]));
            cnt[jj] += __popcll(__ballot(Kk[1] > Kj[jj]));
            cnt[jj] += __popcll(__ballot(Kk[2] > Kj[jj]));
            cnt[jj] += __popcll(__ballot(Kk[3] > Kj[jj]));
        }
    }

    #pragma unroll
    for (int jj = 0; jj < 8; ++jj) {
        if (lane == jj) fsorted[cnt[jj]] = pred[jbase + jj];
    }
}

// Kernel 2: closed-form loss from sorted f, fp32 with shuffle-scan.
//   a_i = e^{f_i} + e^{f_{N-1-i}},  b_i = e^{-f_i} + e^{-f_{N-1-i}}
//   E_i, G_i = suffix sums;  denom_i = E_i*G_i - (N - 2i)  (>= 2, no cancellation)
//   loss = - sum_i [ (f_i - f_{N-1-i}) - log(denom_i) ]
__global__ void __launch_bounds__(1024) loss_kernel(
    const float* __restrict__ f,
    float* __restrict__ out)
{
    __shared__ float sWA[16], sWB[16];
    __shared__ double sL[16];

    const int t    = threadIdx.x;
    const int lane = t & 63;
    const int w    = t >> 6;

    const float4 fi4 = *reinterpret_cast<const float4*>(f + 4 * t);
    const float4 fo4 = *reinterpret_cast<const float4*>(f + (N - 4 - 4 * t));
    float fi[4] = {fi4.x, fi4.y, fi4.z, fi4.w};
    float fo[4] = {fo4.w, fo4.z, fo4.y, fo4.x};   // reversed

    float a[4], b[4];
    float sa = 0.f, sb = 0.f;
    #pragma unroll
    for (int c = 0; c < 4; ++c) {
        const float e1 = __expf(fi[c]);
        const float e2 = __expf(fo[c]);
        const float m1 = __frcp_rn(e1);
        const float m2 = __frcp_rn(e2);
        a[c] = e1 + e2;
        b[c] = m1 + m2;
        sa += a[c];
        sb += b[c];
    }

    // wave-64 inclusive shuffle scan of per-thread sums
    float va = sa, vb = sb;
    #pragma unroll
    for (int off = 1; off < 64; off <<= 1) {
        const float ua = __shfl_up(va, off, 64);
        const float ub = __shfl_up(vb, off, 64);
        if (lane >= off) { va += ua; vb += ub; }
    }
    if (lane == 63) { sWA[w] = va; sWB[w] = vb; }
    __syncthreads();

    // totals + exclusive prefix of wave sums (16 broadcast LDS reads)
    float TA = 0.f, TB = 0.f, wpA = 0.f, wpB = 0.f;
    #pragma unroll
    for (int ww = 0; ww < 16; ++ww) {
        const float xa = sWA[ww];
        const float xb = sWB[ww];
        TA += xa; TB += xb;
        if (ww < w) { wpA += xa; wpB += xb; }
    }
    const float exA = wpA + (va - sa);   // sum of a over elements before this thread's chunk
    const float exB = wpB + (vb - sb);

    float runA = 0.f, runB = 0.f;
    double lsum = 0.0;
    #pragma unroll
    for (int c = 0; c < 4; ++c) {
        const int i = 4 * t + c;
        const float E = TA - exA - runA;    // suffix sum starting at i
        const float G = TB - exB - runB;
        runA += a[c];
        runB += b[c];
        float denom = E * G - (float)(N - 2 * i);
        if (denom <= 0.f) denom = 1e-8f;
        lsum += (double)(fi[c] - fo[c]) - (double)__logf(denom);
    }

    // block reduce
    #pragma unroll
    for (int off = 32; off > 0; off >>= 1)
        lsum += __shfl_down(lsum, off, 64);
    if (lane == 0) sL[w] = lsum;
    __syncthreads();
    if (t == 0) {
        double tot = 0.0;
        #pragma unroll
        for (int ww = 0; ww < 16; ++ww) tot += sL[ww];
        out[0] = (float)(-tot);
    }
}

extern "C" void kernel_launch(void* const* d_in, const int* in_sizes, int n_in,
                              void* d_out, int out_size, void* d_ws, size_t ws_size,
                              hipStream_t stream)
{
    const float* pred   = (const float*)d_in[0];
    const float* target = (const float*)d_in[1];
    float* out = (float*)d_out;
    float* fsorted = (float*)d_ws;   // 32 KB scratch

    rank_kernel<<<256, 256, 0, stream>>>(pred, target, fsorted);
    loss_kernel<<<1, 1024, 0, stream>>>(fsorted, out);
}